// Round 6
// baseline (71.464 us; speedup 1.0000x reference)
//
#include <hip/hip_runtime.h>
#include <stdint.h>

#define D_IN    2048
#define NT      15
#define PPT     14359      // 7*(2048+1) + 8*2
#define NVALID  60         // 15 trees * 4 used internal nodes

typedef __bf16   bf16x8 __attribute__((ext_vector_type(8)));
typedef float    f32x4  __attribute__((ext_vector_type(4)));
typedef uint32_t u32x4  __attribute__((ext_vector_type(4)));

#define WAITV(n) asm volatile("s_waitcnt vmcnt(" #n ")" ::: "memory")
#define WAITL0   asm volatile("s_waitcnt lgkmcnt(0)" ::: "memory")
#define SCHEDB   __builtin_amdgcn_sched_barrier(0)

// pack two floats -> (hi bf16 pair, lo bf16 pair); lo = residual of truncation
#define CVT_PAIR(P, Q, HW, LW) do {                                   \
    uint32_t _up = __float_as_uint(P), _uq = __float_as_uint(Q);      \
    uint32_t _mp = _up & 0xFFFF0000u, _mq = _uq & 0xFFFF0000u;        \
    (HW) = (_up >> 16) | _mq;                                         \
    float _lp = (P) - __uint_as_float(_mp);                           \
    float _lq = (Q) - __uint_as_float(_mq);                           \
    (LW) = (__float_as_uint(_lp) >> 16) |                             \
           (__float_as_uint(_lq) & 0xFFFF0000u);                      \
  } while (0)

__device__ __forceinline__ void cvt8(const f32x4 A, const f32x4 B,
                                     u32x4& hi, u32x4& lo) {
  CVT_PAIR(A[0], A[1], hi[0], lo[0]);
  CVT_PAIR(A[2], A[3], hi[1], lo[1]);
  CVT_PAIR(B[0], B[1], hi[2], lo[2]);
  CVT_PAIR(B[2], B[3], hi[3], lo[3]);
}

__device__ __forceinline__ f32x4 gload4(const float* p) {
  f32x4 r;
  asm volatile("global_load_dwordx4 %0, %1, off" : "=v"(r) : "v"(p) : "memory");
  return r;
}
__device__ __forceinline__ u32x4 dsread16(uint32_t addr) {
  u32x4 r;
  asm volatile("ds_read_b128 %0, %1" : "=v"(r) : "v"(addr) : "memory");
  return r;
}
__device__ __forceinline__ void dswrite16(uint32_t addr, u32x4 v) {
  asm volatile("ds_write_b128 %0, %1" :: "v"(addr), "v"(v) : "memory");
}

// One K-step (BK=64). Single-kernel protocol: counted vmcnt, 1 barrier/iter,
// 3 LDS slab bufs, 3 W reg-bufs, 3 A reg-bufs, distance-3 loads (8 vmem/iter).
//   top: vmcnt(WN) [drains W(t+1),A(t+1)]; barrier
//   ds_read 16 B-frags of buf[t%3]
//   cvt W(t+1) (landed) -> 4 ds_write to buf[(t+1)%3]   [slot-safe, see proof]
//   cvt A(t)
//   lgkmcnt(0)  -> my reads AND writes drained before next barrier
//   issue W(t+3)->wbuf[t%3], A(t+3)->abuf[t%3]
//   24 MFMA
#define ITERATION(tt, BUF, WBUF, WCON, WISS, RC, WN, ISSUE, DOWRITE)           \
  {                                                                            \
    WAITV(WN); SCHEDB;                                                         \
    __builtin_amdgcn_s_barrier();                                              \
    const uint32_t bb = sbase + (BUF) * 16384 + l16;                           \
    u32x4 bfr[16];                                                             \
    _Pragma("unroll")                                                          \
    for (int q = 0; q < 16; ++q) bfr[q] = dsread16(bb + q * 1024);             \
    if (DOWRITE) {                                                             \
      f32x4 s0 = WCON[0] * vm0, s1 = WCON[1] * vm0;                            \
      f32x4 s2 = WCON[2] * vm1, s3 = WCON[3] * vm1;                            \
      u32x4 h0, lo0, h1, lo1;                                                  \
      cvt8(s0, s1, h0, lo0);                                                   \
      cvt8(s2, s3, h1, lo1);                                                   \
      const uint32_t wbb = sbase + (WBUF) * 16384 + l16;                       \
      dswrite16(wbb + cp0 * 2048,        h0);                                  \
      dswrite16(wbb + cp0 * 2048 + 1024, lo0);                                 \
      dswrite16(wbb + cp1 * 2048,        h1);                                  \
      dswrite16(wbb + cp1 * 2048 + 1024, lo1);                                 \
    }                                                                          \
    u32x4 ah0, al0, ah1, al1;                                                  \
    cvt8(RC[0], RC[1], ah0, al0);                                              \
    cvt8(RC[2], RC[3], ah1, al1);                                              \
    WAITL0; SCHEDB;                                                            \
    if (ISSUE) {                                                               \
      const int t3 = (tt) + 3;                                                 \
      WISS[0] = gload4(wsrc0 + t3 * 64);  WISS[1] = gload4(wsrc0 + t3 * 64 + 4); \
      WISS[2] = gload4(wsrc1 + t3 * 64);  WISS[3] = gload4(wsrc1 + t3 * 64 + 4); \
      const float* ap = xbase + t3 * 64;                                       \
      RC[0] = gload4(ap);      RC[1] = gload4(ap + 4);                         \
      RC[2] = gload4(ap + 32); RC[3] = gload4(ap + 36);                        \
    }                                                                          \
    _Pragma("unroll")                                                          \
    for (int f = 0; f < 4; ++f) {                                              \
      bf16x8 bh = __builtin_bit_cast(bf16x8, bfr[f * 2]);                      \
      bf16x8 bl = __builtin_bit_cast(bf16x8, bfr[f * 2 + 1]);                  \
      bf16x8 Ah = __builtin_bit_cast(bf16x8, ah0);                             \
      bf16x8 Al = __builtin_bit_cast(bf16x8, al0);                             \
      acc[f] = __builtin_amdgcn_mfma_f32_16x16x32_bf16(Ah, bh, acc[f], 0,0,0); \
      acc[f] = __builtin_amdgcn_mfma_f32_16x16x32_bf16(Al, bh, acc[f], 0,0,0); \
      acc[f] = __builtin_amdgcn_mfma_f32_16x16x32_bf16(Ah, bl, acc[f], 0,0,0); \
    }                                                                          \
    _Pragma("unroll")                                                          \
    for (int f = 0; f < 4; ++f) {                                              \
      bf16x8 bh = __builtin_bit_cast(bf16x8, bfr[8 + f * 2]);                  \
      bf16x8 bl = __builtin_bit_cast(bf16x8, bfr[8 + f * 2 + 1]);              \
      bf16x8 Ah = __builtin_bit_cast(bf16x8, ah1);                             \
      bf16x8 Al = __builtin_bit_cast(bf16x8, al1);                             \
      acc[f] = __builtin_amdgcn_mfma_f32_16x16x32_bf16(Ah, bh, acc[f], 0,0,0); \
      acc[f] = __builtin_amdgcn_mfma_f32_16x16x32_bf16(Al, bh, acc[f], 0,0,0); \
      acc[f] = __builtin_amdgcn_mfma_f32_16x16x32_bf16(Ah, bl, acc[f], 0,0,0); \
    }                                                                          \
  }

__global__ __launch_bounds__(256) void tree_fused(
    const float* __restrict__ x,
    const float* __restrict__ tp,
    const float* __restrict__ tw,
    float* __restrict__ out)
{
  __shared__ __align__(1024) unsigned char sB[3 * 16384];   // slab triple buffer
  __shared__ float strips[4][16][65];
  __shared__ float sBias[64];
  __shared__ float sCoef[160];

  const int tid = threadIdx.x;
  const int w   = tid >> 6;        // wave 0..3
  const int l   = tid & 63;
  const int rl  = l & 15;
  const int g   = l >> 4;
  const int l16 = l * 16;

  // ---- prologue A: per-block coef/bias (redundant, trivial) ----
  if (tid < 64) {
    float b = 0.0f;
    if (tid < NVALID) { int t = tid >> 2, i = tid & 3; b = tp[t * PPT + 14336 + i]; }
    sBias[tid] = b;
  } else if (tid < 64 + NT) {
    int t = tid - 64;
    const float* ll = tp + t * PPT + 14343;  // leaf_logits [8][2]
    float d0[8], d1[8];
#pragma unroll
    for (int le = 0; le < 8; ++le) {
      float aa = ll[2 * le], bb2 = ll[2 * le + 1];
      float m = fmaxf(aa, bb2);
      float e0 = __expf(aa - m), e1 = __expf(bb2 - m);
      float inv = 1.0f / (e0 + e1);
      d0[le] = e0 * inv; d1[le] = e1 * inv;
    }
    float ww = tw[t];
    float* c = sCoef + t * 10;
    c[0] = ww * (d0[0] + d0[2] + d0[4] + d0[6]);
    c[1] = ww * (d1[0] + d1[2] + d1[4] + d1[6]);
    c[2] = ww * (d0[1] - d0[2]);
    c[3] = ww * (d1[1] - d1[2]);
    c[4] = ww * (d0[3] - d0[4]);
    c[5] = ww * (d1[3] - d1[4]);
    c[6] = ww * (d0[5] - d0[6]);
    c[7] = ww * (d1[5] - d1[6]);
    c[8] = ww * d0[7];
    c[9] = ww * d1[7];
  }
  __syncthreads();
  WAITV(0);           // clean vmcnt slate before the counted protocol
  SCHEDB;

  // ---- W-gather setup: wave w owns combos c=2w,2w+1; combo c=(h,f)=(c>>2,c&3)
  // chunk pair cp=h*4+f; lane l supplies n=16f+(l&15), k=64*slab+32h+8*(l>>4)+j
  const int c0 = 2 * w,     c1 = 2 * w + 1;
  const int h0_ = c0 >> 2,  f0_ = c0 & 3;
  const int h1_ = c1 >> 2,  f1_ = c1 & 3;
  const int cp0 = h0_ * 4 + f0_;
  const int cp1 = h1_ * 4 + f1_;
  const int n0 = 16 * f0_ + rl;
  const int n1 = 16 * f1_ + rl;
  const float vm0 = (n0 < NVALID) ? 1.0f : 0.0f;
  const float vm1 = (n1 < NVALID) ? 1.0f : 0.0f;
  const float* wsrc0 = tp + (size_t)((n0 < NVALID ? n0 : 0) >> 2) * PPT
                          + ((n0 < NVALID ? n0 : 0) & 3) * D_IN + 32 * h0_ + 8 * g;
  const float* wsrc1 = tp + (size_t)((n1 < NVALID ? n1 : 0) >> 2) * PPT
                          + ((n1 < NVALID ? n1 : 0) & 3) * D_IN + 32 * h1_ + 8 * g;

  const int rowTile = blockIdx.x * 64 + w * 16;
  const float* xbase = x + (size_t)(rowTile + rl) * D_IN + g * 8;
  const uint32_t sbase = (uint32_t)(uintptr_t)&sB[0];

  f32x4 acc[4] = {};
  f32x4 ra0[4], ra1[4], ra2[4];    // A regs, slab%3
  f32x4 wb0[4], wb1[4], wb2[4];    // W regs, slab%3

  // ---- prologue B: issue slabs 0,1,2 (24 vmem); land slab0; write buf0 ----
  {
    wb0[0] = gload4(wsrc0);       wb0[1] = gload4(wsrc0 + 4);
    wb0[2] = gload4(wsrc1);       wb0[3] = gload4(wsrc1 + 4);
    ra0[0] = gload4(xbase);       ra0[1] = gload4(xbase + 4);
    ra0[2] = gload4(xbase + 32);  ra0[3] = gload4(xbase + 36);
    wb1[0] = gload4(wsrc0 + 64);  wb1[1] = gload4(wsrc0 + 68);
    wb1[2] = gload4(wsrc1 + 64);  wb1[3] = gload4(wsrc1 + 68);
    ra1[0] = gload4(xbase + 64);  ra1[1] = gload4(xbase + 68);
    ra1[2] = gload4(xbase + 96);  ra1[3] = gload4(xbase + 100);
    wb2[0] = gload4(wsrc0 + 128); wb2[1] = gload4(wsrc0 + 132);
    wb2[2] = gload4(wsrc1 + 128); wb2[3] = gload4(wsrc1 + 132);
    ra2[0] = gload4(xbase + 128); ra2[1] = gload4(xbase + 132);
    ra2[2] = gload4(xbase + 160); ra2[3] = gload4(xbase + 164);
    WAITV(16); SCHEDB;                         // slab0 (W0,A0) landed
    f32x4 s0 = wb0[0] * vm0, s1 = wb0[1] * vm0;
    f32x4 s2 = wb0[2] * vm1, s3 = wb0[3] * vm1;
    u32x4 h0, lo0, h1, lo1;
    cvt8(s0, s1, h0, lo0);
    cvt8(s2, s3, h1, lo1);
    const uint32_t wbb = sbase + l16;
    dswrite16(wbb + cp0 * 2048,        h0);
    dswrite16(wbb + cp0 * 2048 + 1024, lo0);
    dswrite16(wbb + cp1 * 2048,        h1);
    dswrite16(wbb + cp1 * 2048 + 1024, lo1);
    WAITL0; SCHEDB;
  }

  // ---- main loop: t%3 pattern; iters 0..26 in groups of 3, then 27..31 ----
  for (int tb = 0; tb < 27; tb += 3) {
    ITERATION(tb + 0, 0, 1, wb1, wb0, ra0, 8, 1, 1);
    ITERATION(tb + 1, 1, 2, wb2, wb1, ra1, 8, 1, 1);
    ITERATION(tb + 2, 2, 0, wb0, wb2, ra2, 8, 1, 1);
  }
  ITERATION(27, 0, 1, wb1, wb0, ra0, 8, 1, 1);
  ITERATION(28, 1, 2, wb2, wb1, ra1, 8, 1, 1);
  ITERATION(29, 2, 0, wb0, wb2, ra2, 8, 0, 1);   // no issue (t+3 > 31)
  ITERATION(30, 0, 1, wb1, wb0, ra0, 0, 0, 1);   // drain: W31,A31 needed now
  ITERATION(31, 1, 2, wb2, wb1, ra1, 0, 0, 0);   // pure compute tail

  // ---- epilogue: per-wave strip transpose + folded tree math ----
#pragma unroll
  for (int f = 0; f < 4; ++f)
#pragma unroll
    for (int r = 0; r < 4; ++r)
      strips[w][4 * g + r][16 * f + rl] = acc[f][r];
  WAITL0;

  float o0 = 0.0f, o1 = 0.0f;
#pragma unroll
  for (int jt = 0; jt < 4; ++jt) {
    int t = g + 4 * jt;
    if (t < NT) {
      const float* cf = sCoef + t * 10;
      float dd[4];
#pragma unroll
      for (int i = 0; i < 4; ++i) {
        float z = strips[w][rl][4 * t + i] + sBias[4 * t + i];
        dd[i] = 1.0f / (1.0f + __expf(-z));
      }
      float s = 1.0f / (4.0f + dd[3] + 1e-8f);
      o0 += s * (cf[0] + dd[0] * cf[2] + dd[1] * cf[4] + dd[2] * cf[6] + dd[3] * cf[8]);
      o1 += s * (cf[1] + dd[0] * cf[3] + dd[1] * cf[5] + dd[2] * cf[7] + dd[3] * cf[9]);
    }
  }
  o0 += __shfl_xor(o0, 16); o0 += __shfl_xor(o0, 32);
  o1 += __shfl_xor(o1, 16); o1 += __shfl_xor(o1, 32);
  if (l < 16) {
    ((float2*)out)[rowTile + rl] = make_float2(o0, o1);
  }
}

// ---------------- launch ------------------------------------------------------
extern "C" void kernel_launch(void* const* d_in, const int* in_sizes, int n_in,
                              void* d_out, int out_size, void* d_ws, size_t ws_size,
                              hipStream_t stream) {
  (void)in_sizes; (void)n_in; (void)out_size; (void)d_ws; (void)ws_size;
  const float* x  = (const float*)d_in[0];
  const float* tp = (const float*)d_in[1];
  const float* tw = (const float*)d_in[2];
  float* out = (float*)d_out;

  tree_fused<<<512, 256, 0, stream>>>(x, tp, tw, out);
}